// Round 8
// baseline (287.637 us; speedup 1.0000x reference)
//
#include <hip/hip_runtime.h>
#include <hip/hip_bf16.h>

typedef _Float16 half8v __attribute__((ext_vector_type(8)));
typedef _Float16 half4v __attribute__((ext_vector_type(4)));
typedef _Float16 half2v __attribute__((ext_vector_type(2)));
typedef __fp16   fp16x2 __attribute__((ext_vector_type(2)));
typedef __attribute__((ext_vector_type(4))) float floatx4;

#define LOG2E_OVER_8 0.18033688011112042f

// ---------------- Kernel 0: W (3 x 512x64 fp32) -> Wt fp16 [3][64][512] -----
__global__ __launch_bounds__(256) void wtrans_k(const float* __restrict__ Wq,
                                                const float* __restrict__ Wk,
                                                const float* __restrict__ Wv,
                                                _Float16* __restrict__ Wt) {
    int idx = blockIdx.x * 256 + threadIdx.x;   // 98304
    int p = idx >> 15, rem = idx & 32767;
    int k = rem >> 6;      // 0..511
    int n = rem & 63;      // lane-fast -> coalesced read
    const float* W = (p == 0) ? Wq : ((p == 1) ? Wk : Wv);
    Wt[p * 32768 + n * 512 + k] = (_Float16)W[k * 64 + n];
}

// ---------------- Kernel 1: QKV projection, LDS-staged x --------------------
// grid 1024 x 256 (4 waves). Block = 16-row x-tile; wave = 3 N-tiles of 12.
// x staged coalesced fp32->fp16 into LDS once (1 barrier), then pure
// ds_read_b128 -> mfma. Q pre-scaled by log2(e)/8.
#define XS_STRIDE 536   // halves; 1072 B = 67*16 (b128-aligned, ~4-way max)
__global__ __launch_bounds__(256) void proj_k(const float* __restrict__ x,
                                              const _Float16* __restrict__ Wt,
                                              const float* __restrict__ bq,
                                              const float* __restrict__ bk,
                                              const float* __restrict__ bv,
                                              _Float16* __restrict__ Qh,
                                              _Float16* __restrict__ Kh,
                                              _Float16* __restrict__ Vh) {
    __shared__ _Float16 xs[16 * XS_STRIDE];   // 17,152 B

    int tid = threadIdx.x, l = tid & 63, wv = tid >> 6;
    int m = l & 15, quad = l >> 4;
    int row0 = blockIdx.x * 16;

    // stage x tile (16 x 512 fp32 = 32 KB) coalesced, cvt to fp16 (RNE)
#pragma unroll
    for (int i = 0; i < 8; i++) {
        int idx = tid + i * 256;              // 0..2047 float4 groups
        int row = idx >> 7, c4 = idx & 127;
        float4 v = *(const float4*)(x + (row0 + row) * 512 + c4 * 4);
        union { half2v h[2]; uint2 u; } cv;
        cv.h[0][0] = (_Float16)v.x; cv.h[0][1] = (_Float16)v.y;
        cv.h[1][0] = (_Float16)v.z; cv.h[1][1] = (_Float16)v.w;
        *(uint2*)(xs + row * XS_STRIDE + c4 * 4) = cv.u;
    }
    __syncthreads();

    const _Float16* wbase = Wt + (wv * 48 + m) * 512 + quad * 8;
    const _Float16* arow  = xs + m * XS_STRIDE + quad * 8;

    floatx4 acc[3];
#pragma unroll
    for (int i = 0; i < 3; i++) acc[i] = (floatx4)(0.f);

#pragma unroll 4
    for (int kc = 0; kc < 16; kc++) {
        half8v a = *(const half8v*)(arow + kc * 32);
#pragma unroll
        for (int ct = 0; ct < 3; ct++) {
            half8v b = *(const half8v*)(wbase + ct * 8192 + kc * 32);
            acc[ct] = __builtin_amdgcn_mfma_f32_16x16x32_f16(a, b, acc[ct], 0, 0, 0);
        }
    }

#pragma unroll
    for (int ct = 0; ct < 3; ct++) {
        int ctg = wv * 3 + ct;
        int col = ctg * 16 + m;
        float bias = (ctg < 4) ? bq[col] : ((ctg < 8) ? bk[col - 64] : bv[col - 128]);
        if (ctg < 8) {
            _Float16* dst = (ctg < 4) ? Qh : Kh;
            float scl = (ctg < 4) ? LOG2E_OVER_8 : 1.0f;
            int d = (ctg & 3) * 16 + m;
#pragma unroll
            for (int r = 0; r < 4; r++) {
                int row = row0 + quad * 4 + r;
                dst[row * 64 + d] = (_Float16)((acc[ct][r] + bias) * scl);
            }
        } else {
            int d = (ctg - 8) * 16 + m;
            int row = row0 + quad * 4;
            int bb = row >> 12, sq = row & 4095;
            union { _Float16 h[4]; unsigned long long u; } pk;
#pragma unroll
            for (int r = 0; r < 4; r++) pk.h[r] = (_Float16)(acc[ct][r] + bias);
            *(unsigned long long*)(Vh + ((bb * 64 + d) * 4096 + sq)) = pk.u;
        }
    }
}

// ---------------- Kernel 2: attention, layout-matched P ---------------------
// S^T = K Q^T via mfma_16x16x32_f16: C-layout (row=key=quad*4+r, col=q=lane&15)
// == B-layout of mfma_16x16x16_f16 (k=quad*4+j, n=lane&15). exp+pack in-lane,
// NO cross-lane ops / LDS / barriers in the loop. Wave = 16 q x 1024 keys.
// grid 1024 = qt(64) x [os(4) x b(4)]; bid&15 -> XCD-aligned K/V slices.
__global__ __launch_bounds__(256) void attn_k(const _Float16* __restrict__ Qh,
                                              const _Float16* __restrict__ Kh,
                                              const _Float16* __restrict__ Vh,
                                              const int* __restrict__ mask,
                                              float* __restrict__ Np,
                                              float* __restrict__ Dp) {
    __shared__ float T[4][16 * 68];   // epilogue transpose only (17.4 KB)

    int tid = threadIdx.x, l = tid & 63, wv = tid >> 6;
    int m = l & 15, quad = l >> 4;
    int bid = blockIdx.x;
    int qt = bid >> 4, grp = bid & 15, os = grp >> 2, b = grp & 3;
    int q0 = qt * 64 + wv * 16;
    int kbase = os * 1024;

    const int* maskb = mask + b * 4096 + kbase;
    int az = 0;
#pragma unroll
    for (int i = 0; i < 16; i++) az |= (maskb[l + i * 64] == 0);
    const bool hasz = __any(az);

    // Q B-frags (16x16x32: n=q=lane&15, k=d=quad*8+j), d-chunks 0/1
    const _Float16* Qg = Qh + (b * 4096 + q0 + m) * 64 + quad * 8;
    half8v qf0 = *(const half8v*)(Qg);
    half8v qf1 = *(const half8v*)(Qg + 32);

    const _Float16* Kg = Kh + (b * 4096 + kbase + m) * 64 + quad * 8;
    const _Float16* Vg = Vh + b * 262144 + m * 4096 + kbase + quad * 4;

    floatx4 oacc[4];
#pragma unroll
    for (int i = 0; i < 4; i++) oacc[i] = (floatx4)(0.f);
    float dl = 0.f;

#pragma unroll 2
    for (int kt = 0; kt < 32; kt++) {
        int k32 = kt * 32;
        half4v pb[2];
#pragma unroll
        for (int t = 0; t < 2; t++) {
            // S^T tile: A=K (m=key), chained over d-chunks
            const _Float16* kp = Kg + (k32 + t * 16) * 64;
            half8v k0 = *(const half8v*)(kp);
            half8v k1 = *(const half8v*)(kp + 32);
            floatx4 sf = (floatx4)(0.f);
            sf = __builtin_amdgcn_mfma_f32_16x16x32_f16(k0, qf0, sf, 0, 0, 0);
            sf = __builtin_amdgcn_mfma_f32_16x16x32_f16(k1, qf1, sf, 0, 0, 0);
            // exp2 (Q pre-scaled; |logit|<=~3), denominator, pack (RTZ on P>0)
            float p0 = exp2f(sf[0]), p1 = exp2f(sf[1]);
            float p2 = exp2f(sf[2]), p3 = exp2f(sf[3]);
            dl += (p0 + p1) + (p2 + p3);
            if (hasz) {   // post-softmax -inf fill semantics (rare path)
                int kg = k32 + t * 16 + quad * 4;
                if (maskb[kg + 0] == 0) p0 = -__builtin_inff();
                if (maskb[kg + 1] == 0) p1 = -__builtin_inff();
                if (maskb[kg + 2] == 0) p2 = -__builtin_inff();
                if (maskb[kg + 3] == 0) p3 = -__builtin_inff();
            }
            union { fp16x2 h[2]; half4v h4; } pu;
            pu.h[0] = __builtin_amdgcn_cvt_pkrtz(p0, p1);
            pu.h[1] = __builtin_amdgcn_cvt_pkrtz(p2, p3);
            pb[t] = pu.h4;   // B-frag: k=quad*4+j, n=q  (== S^T C-layout!)
        }
        // O^T += V^T P^T : A=V^T (m=d, k=key=quad*4+j), per 16-d tile
#pragma unroll
        for (int dt = 0; dt < 4; dt++) {
            const _Float16* vp = Vg + dt * 65536 + k32;
            half4v v0 = *(const half4v*)(vp);
            half4v v1 = *(const half4v*)(vp + 16);
            oacc[dt] = __builtin_amdgcn_mfma_f32_16x16x16f16(v0, pb[0], oacc[dt], 0, 0, 0);
            oacc[dt] = __builtin_amdgcn_mfma_f32_16x16x16f16(v1, pb[1], oacc[dt], 0, 0, 0);
        }
    }

    // denominator: lane holds q=m partial over its keys; combine 4 quads
    dl += __shfl_xor(dl, 16, 64);
    dl += __shfl_xor(dl, 32, 64);
    int rowbase = os * 16384 + b * 4096 + q0;
    if (l < 16) Dp[rowbase + l] = dl;

    // epilogue: O^T (d=dt*16+quad*4+r, q=m) -> row-major via wave-private LDS
    float* Tw = &T[wv][0];
#pragma unroll
    for (int dt = 0; dt < 4; dt++)
#pragma unroll
        for (int r = 0; r < 4; r++)
            Tw[m * 68 + dt * 16 + quad * 4 + r] = oacc[dt][r];
    __builtin_amdgcn_s_waitcnt(0);   // wave-private LDS: no barrier needed
#pragma unroll
    for (int g = 0; g < 4; g++) {
        int idx = g * 64 + l;
        int row = idx >> 4, c4 = (idx & 15) * 4;
        float4 v = *(const float4*)(Tw + row * 68 + c4);
        *(float4*)(Np + (rowbase + row) * 64 + c4) = v;
    }
}

// ---------------- Kernel 3: combine 4 key-split partials --------------------
__global__ __launch_bounds__(256) void combine_k(const float* __restrict__ Np,
                                                 const float* __restrict__ Dp,
                                                 float* __restrict__ out) {
    int g = blockIdx.x * 256 + threadIdx.x;   // 1,048,576
    int row = g >> 6;
    float nu = 0.f, d = 0.f;
#pragma unroll
    for (int sp = 0; sp < 4; sp++) {
        nu += Np[sp * 1048576 + g];
        d  += Dp[sp * 16384 + row];
    }
    out[g] = nu / d;
}

extern "C" void kernel_launch(void* const* d_in, const int* in_sizes, int n_in,
                              void* d_out, int out_size, void* d_ws, size_t ws_size,
                              hipStream_t stream) {
    const float* x  = (const float*)d_in[0];
    const int* mask = (const int*)d_in[1];
    const float* Wq = (const float*)d_in[2];
    const float* bq = (const float*)d_in[3];
    const float* Wk = (const float*)d_in[4];
    const float* bk = (const float*)d_in[5];
    const float* Wv = (const float*)d_in[6];
    const float* bv = (const float*)d_in[7];
    float* out = (float*)d_out;

    char* ws = (char*)d_ws;
    _Float16* Wt = (_Float16*)(ws);              // 192 KB fp16 [3][64][512]
    _Float16* Qh = (_Float16*)(ws + 0x40000);    // 2 MB fp16 [B*S][64]
    _Float16* Kh = (_Float16*)(ws + 0x240000);   // 2 MB
    _Float16* Vh = (_Float16*)(ws + 0x440000);   // 2 MB fp16 [B][64][S]
    float*    Dp = (float*)(ws + 0x640000);      // 256 KB [4][16384]
    float*    Np = (float*)(ws + 0x6C0000);      // 16.78 MB [4][16384][64]

    wtrans_k<<<384, 256, 0, stream>>>(Wq, Wk, Wv, Wt);
    proj_k<<<1024, 256, 0, stream>>>(x, Wt, bq, bk, bv, Qh, Kh, Vh);
    attn_k<<<1024, 256, 0, stream>>>(Qh, Kh, Vh, mask, Np, Dp);
    combine_k<<<4096, 256, 0, stream>>>(Np, Dp, out);
}

// Round 9
// 160.787 us; speedup vs baseline: 1.7889x; 1.7889x over previous
//
#include <hip/hip_runtime.h>
#include <hip/hip_bf16.h>

typedef _Float16 half8v __attribute__((ext_vector_type(8)));
typedef _Float16 half4v __attribute__((ext_vector_type(4)));
typedef _Float16 half2v __attribute__((ext_vector_type(2)));
typedef __fp16   fp16x2 __attribute__((ext_vector_type(2)));
typedef __attribute__((ext_vector_type(4))) float floatx4;

#define LOG2E_OVER_8 0.18033688011112042f

// ===== Frag-order layouts (all produced by us, consumed by attn/proj) =======
// Kh: A-frag chunks for mfma_f32_16x16x32_f16 S^T:
//     chunk(t16,c) = [quad(4)][m(16)][8 halves]: lane(m,quad) = K[key=t16*16+m][d=c*32+quad*8..+8]
//     addr_halves = ((t16*2 + c)*64 + quad*16 + m)*8
// Qh: B-frag chunks, same shape with m=q%16: ((qt*2 + c)*64 + quad*16 + q%16)*8
// Vh: A-frag chunks for mfma 16x16x16 PV (V^T): chunk(t64,dt,ktp) 1 KB:
//     lane(m,quad) 16B = keys[t64*64+ktp*32+quad*4 + 0..3] (j0-3) and [+16 +0..3] (j4-7), d=dt*16+m
//     addr_halves = (((t64*8) + dt*2 + ktp)*64 + quad*16 + m)*8
// Wt: B-frag chunks: ((ctg*16+kc)*64 + quad*16 + m)*8, ctg 0..11, kc 0..15

// ---------------- Kernel 0: W -> frag-order Wt fp16 -------------------------
__global__ __launch_bounds__(256) void wtrans_k(const float* __restrict__ Wq,
                                                const float* __restrict__ Wk,
                                                const float* __restrict__ Wv,
                                                _Float16* __restrict__ Wt) {
    int idx = blockIdx.x * 256 + threadIdx.x;   // 98304 = 3*512*64
    int p = idx >> 15, rem = idx & 32767;
    int k = rem >> 6;      // 0..511 input row
    int n = rem & 63;      // 0..63 input col (lane-fast -> coalesced read)
    const float* W = (p == 0) ? Wq : ((p == 1) ? Wk : Wv);
    int ctg = p * 4 + (n >> 4), m = n & 15;
    int kc = k >> 5, quad = (k >> 3) & 3, j = k & 7;
    Wt[(((ctg << 4) + kc) * 64 + (quad << 4) + m) * 8 + j] = (_Float16)W[k * 64 + n];
}

// ---------------- Kernel 1: QKV projection ---------------------------------
// grid 1024 x 256 (4 waves). Block = 16-row x-tile; wave = 3 N-tiles of 12.
// x: coalesced fp32->fp16 LDS stage; W: frag-order coalesced 1KB chunk loads.
#define XS_STRIDE 536
__global__ __launch_bounds__(256) void proj_k(const float* __restrict__ x,
                                              const _Float16* __restrict__ Wt,
                                              const float* __restrict__ bq,
                                              const float* __restrict__ bk,
                                              const float* __restrict__ bv,
                                              _Float16* __restrict__ Qh,
                                              _Float16* __restrict__ Kh,
                                              _Float16* __restrict__ Vh) {
    __shared__ _Float16 xs[16 * XS_STRIDE];   // 17,152 B

    int tid = threadIdx.x, l = tid & 63, wv = tid >> 6;
    int m = l & 15, quad = l >> 4;
    int row0 = blockIdx.x * 16;

#pragma unroll
    for (int i = 0; i < 8; i++) {
        int idx = tid + i * 256;              // 2048 float4 groups
        int row = idx >> 7, c4 = idx & 127;
        float4 v = *(const float4*)(x + (row0 + row) * 512 + c4 * 4);
        union { half2v h[2]; uint2 u; } cv;
        cv.h[0][0] = (_Float16)v.x; cv.h[0][1] = (_Float16)v.y;
        cv.h[1][0] = (_Float16)v.z; cv.h[1][1] = (_Float16)v.w;
        *(uint2*)(xs + row * XS_STRIDE + c4 * 4) = cv.u;
    }
    __syncthreads();

    const _Float16* arow = xs + m * XS_STRIDE + quad * 8;

    floatx4 acc[3];
#pragma unroll
    for (int i = 0; i < 3; i++) acc[i] = (floatx4)(0.f);

#pragma unroll 4
    for (int kc = 0; kc < 16; kc++) {
        half8v a = *(const half8v*)(arow + kc * 32);
#pragma unroll
        for (int ct = 0; ct < 3; ct++) {
            int ctg = wv * 3 + ct;
            half8v b = *(const half8v*)(Wt + (((ctg << 4) + kc) * 64 + l) * 8);
            acc[ct] = __builtin_amdgcn_mfma_f32_16x16x32_f16(a, b, acc[ct], 0, 0, 0);
        }
    }

#pragma unroll
    for (int ct = 0; ct < 3; ct++) {
        int ctg = wv * 3 + ct;
        int col = ctg * 16 + m;
        float bias = (ctg < 4) ? bq[col] : ((ctg < 8) ? bk[col - 64] : bv[col - 128]);
        if (ctg < 8) {
            _Float16* dst = (ctg < 4) ? Qh : Kh;
            float scl = (ctg < 4) ? LOG2E_OVER_8 : 1.0f;
            int dd = (ctg & 3) * 16 + m;                 // d 0..63
            int c = dd >> 5, quadQ = (dd >> 3) & 3, j = dd & 7;
#pragma unroll
            for (int r = 0; r < 4; r++) {
                int row = row0 + quad * 4 + r;
                int chunk = ((row >> 4) << 1) + c;
                dst[(chunk * 64 + quadQ * 16 + (row & 15)) * 8 + j] =
                    (_Float16)((acc[ct][r] + bias) * scl);
            }
        } else {
            int dt = ctg - 8;                            // 0..3, mV = m
            int t64 = row0 >> 6, ktp = (row0 >> 5) & 1, half = (row0 >> 4) & 1;
            int chunk = t64 * 8 + dt * 2 + ktp;
            union { _Float16 h[4]; unsigned long long u; } pk;
#pragma unroll
            for (int r = 0; r < 4; r++) pk.h[r] = (_Float16)(acc[ct][r] + bias);
            *(unsigned long long*)(Vh + (chunk * 64 + quad * 16 + m) * 8 + half * 4) = pk.u;
        }
    }
}

// ---------------- Kernel 2: attention --------------------------------------
// grid 512 = qblk(32) x [os(4) x b(4)] (bid&15 -> XCD-pinned K/V slice).
// Block: 128 q (4 waves x 32 q), all 1024 keys of the os-slice.
// K+V 64-key tiles (16 KB) LDS double-buffered via coalesced reg round-trip;
// ONE barrier per tile (writes target buffer last read 2 iters ago).
// Frag reads stride-1 from LDS (conflict-free). Register-resident P:
// S^T (16x16x32, C: row=key=quad*4+r, col=q=lane&15) feeds PV (16x16x16) as B.
__global__ __launch_bounds__(256) void attn_k(const _Float16* __restrict__ Qh,
                                              const _Float16* __restrict__ Kh,
                                              const _Float16* __restrict__ Vh,
                                              const int* __restrict__ mask,
                                              float* __restrict__ Np,
                                              float* __restrict__ Dp) {
    __shared__ __align__(16) unsigned char buf[2][16384];

    int tid = threadIdx.x, l = tid & 63, wv = tid >> 6;
    int m = l & 15, quad = l >> 4;
    int bid = blockIdx.x;
    int qblk = bid >> 4, grp = bid & 15, os = grp >> 2, b = grp & 3;
    int q0 = qblk * 128 + wv * 32;       // within batch

    const int* maskb = mask + b * 4096 + os * 1024;
    int az = 0;
#pragma unroll
    for (int i = 0; i < 16; i++) az |= (maskb[l + i * 64] == 0);
    const bool hasz = __any(az);

    // Q B-frags for 2 q-tiles (coalesced frag-order loads)
    int qt_g = (b * 4096 + q0) >> 4;
    half8v qf[2][2];
#pragma unroll
    for (int qt = 0; qt < 2; qt++)
#pragma unroll
        for (int c = 0; c < 2; c++)
            qf[qt][c] = *(const half8v*)(Qh + (((qt_g + qt) * 2 + c) * 64 + l) * 8);

    const uint4* kh4 = (const uint4*)Kh;
    const uint4* vh4 = (const uint4*)Vh;
    int tb0 = (b * 64 + os * 16) * 512;  // uint4 idx of tile 0 (8 chunks x 64)

    floatx4 oacc[2][4];
#pragma unroll
    for (int qt = 0; qt < 2; qt++)
#pragma unroll
        for (int dt = 0; dt < 4; dt++) oacc[qt][dt] = (floatx4)(0.f);
    float dl[2] = {0.f, 0.f};

    uint4 stg[2][4];
    auto load_tile = [&](int t, uint4* s) {
#pragma unroll
        for (int i = 0; i < 4; i++) {
            int idx = tid + i * 256;     // 0..1023: first 512 = K, last 512 = V
            s[i] = (i < 2) ? kh4[tb0 + t * 512 + idx]
                           : vh4[tb0 + t * 512 + (idx - 512)];
        }
    };
    load_tile(0, stg[0]);

#pragma unroll 2
    for (int t = 0; t < 16; t++) {
        unsigned char* bw = buf[t & 1];
#pragma unroll
        for (int i = 0; i < 4; i++)
            *(uint4*)(bw + (tid + i * 256) * 16) = stg[t & 1][i];
        if (t + 1 < 16) load_tile(t + 1, stg[(t + 1) & 1]);
        __syncthreads();

        const unsigned char* bk = bw;
        const unsigned char* bv = bw + 8192;
        uint4 vv[4];
#pragma unroll
        for (int sub = 0; sub < 4; sub++) {
            half8v k0 = *(const half8v*)(bk + (sub * 2 + 0) * 1024 + l * 16);
            half8v k1 = *(const half8v*)(bk + (sub * 2 + 1) * 1024 + l * 16);
            if ((sub & 1) == 0) {
#pragma unroll
                for (int dt = 0; dt < 4; dt++)
                    vv[dt] = *(const uint4*)(bv + (dt * 2 + (sub >> 1)) * 1024 + l * 16);
            }
            half4v pb[2];
#pragma unroll
            for (int qt = 0; qt < 2; qt++) {
                floatx4 sf = (floatx4)(0.f);
                sf = __builtin_amdgcn_mfma_f32_16x16x32_f16(k0, qf[qt][0], sf, 0, 0, 0);
                sf = __builtin_amdgcn_mfma_f32_16x16x32_f16(k1, qf[qt][1], sf, 0, 0, 0);
                float p0 = exp2f(sf[0]), p1 = exp2f(sf[1]);
                float p2 = exp2f(sf[2]), p3 = exp2f(sf[3]);
                dl[qt] += (p0 + p1) + (p2 + p3);
                if (hasz) {   // post-softmax -inf fill (rare path)
                    int kg = t * 64 + sub * 16 + quad * 4;
                    if (maskb[kg + 0] == 0) p0 = -__builtin_inff();
                    if (maskb[kg + 1] == 0) p1 = -__builtin_inff();
                    if (maskb[kg + 2] == 0) p2 = -__builtin_inff();
                    if (maskb[kg + 3] == 0) p3 = -__builtin_inff();
                }
                union { fp16x2 h[2]; half4v h4; } pu;
                pu.h[0] = __builtin_amdgcn_cvt_pkrtz(p0, p1);
                pu.h[1] = __builtin_amdgcn_cvt_pkrtz(p2, p3);
                pb[qt] = pu.h4;
            }
#pragma unroll
            for (int dt = 0; dt < 4; dt++) {
                union { uint4 u; half4v h[2]; } vc; vc.u = vv[dt];
                half4v va = vc.h[sub & 1];
                oacc[0][dt] = __builtin_amdgcn_mfma_f32_16x16x16f16(va, pb[0], oacc[0][dt], 0, 0, 0);
                oacc[1][dt] = __builtin_amdgcn_mfma_f32_16x16x16f16(va, pb[1], oacc[1][dt], 0, 0, 0);
            }
        }
    }

    // epilogue: den + O^T transpose (wave-private LDS region, reuse buf)
    __syncthreads();
    float* Tw = (float*)(&buf[0][0]) + wv * (16 * 68);   // 4 x 4.35 KB
    int rowb = os * 16384 + b * 4096 + q0;
#pragma unroll
    for (int qt = 0; qt < 2; qt++) {
        float dqt = dl[qt];
        dqt += __shfl_xor(dqt, 16, 64);
        dqt += __shfl_xor(dqt, 32, 64);
        if (l < 16) Dp[rowb + qt * 16 + l] = dqt;
#pragma unroll
        for (int dt = 0; dt < 4; dt++)
#pragma unroll
            for (int r = 0; r < 4; r++)
                Tw[m * 68 + dt * 16 + quad * 4 + r] = oacc[qt][dt][r];
        __builtin_amdgcn_s_waitcnt(0);
#pragma unroll
        for (int g = 0; g < 4; g++) {
            int idx = g * 64 + l;
            int row = idx >> 4, c4 = (idx & 15) * 4;
            float4 v = *(const float4*)(Tw + row * 68 + c4);
            *(float4*)(Np + (rowb + qt * 16 + row) * 64 + c4) = v;
        }
        __builtin_amdgcn_s_waitcnt(0);   // reads done before next qt overwrite
    }
}

// ---------------- Kernel 3: combine 4 key-split partials --------------------
__global__ __launch_bounds__(256) void combine_k(const float* __restrict__ Np,
                                                 const float* __restrict__ Dp,
                                                 float* __restrict__ out) {
    int g = blockIdx.x * 256 + threadIdx.x;   // 1,048,576
    int row = g >> 6;
    float nu = 0.f, d = 0.f;
#pragma unroll
    for (int sp = 0; sp < 4; sp++) {
        nu += Np[sp * 1048576 + g];
        d  += Dp[sp * 16384 + row];
    }
    out[g] = nu / d;
}

extern "C" void kernel_launch(void* const* d_in, const int* in_sizes, int n_in,
                              void* d_out, int out_size, void* d_ws, size_t ws_size,
                              hipStream_t stream) {
    const float* x  = (const float*)d_in[0];
    const int* mask = (const int*)d_in[1];
    const float* Wq = (const float*)d_in[2];
    const float* bq = (const float*)d_in[3];
    const float* Wk = (const float*)d_in[4];
    const float* bk = (const float*)d_in[5];
    const float* Wv = (const float*)d_in[6];
    const float* bv = (const float*)d_in[7];
    float* out = (float*)d_out;

    char* ws = (char*)d_ws;
    _Float16* Wt = (_Float16*)(ws);              // 192 KB frag-order
    _Float16* Qh = (_Float16*)(ws + 0x40000);    // 2 MB frag-order
    _Float16* Kh = (_Float16*)(ws + 0x240000);   // 2 MB frag-order
    _Float16* Vh = (_Float16*)(ws + 0x440000);   // 2 MB V^T frag-order
    float*    Dp = (float*)(ws + 0x640000);      // 256 KB [4][16384]
    float*    Np = (float*)(ws + 0x6C0000);      // 16.78 MB [4][16384][64]

    wtrans_k<<<384, 256, 0, stream>>>(Wq, Wk, Wv, Wt);
    proj_k<<<1024, 256, 0, stream>>>(x, Wt, bq, bk, bv, Qh, Kh, Vh);
    attn_k<<<512, 256, 0, stream>>>(Qh, Kh, Vh, mask, Np, Dp);
    combine_k<<<4096, 256, 0, stream>>>(Np, Dp, out);
}

// Round 10
// 144.816 us; speedup vs baseline: 1.9862x; 1.1103x over previous
//
#include <hip/hip_runtime.h>
#include <hip/hip_bf16.h>

typedef _Float16 half8v __attribute__((ext_vector_type(8)));
typedef _Float16 half4v __attribute__((ext_vector_type(4)));
typedef _Float16 half2v __attribute__((ext_vector_type(2)));
typedef __fp16   fp16x2 __attribute__((ext_vector_type(2)));
typedef __attribute__((ext_vector_type(4))) float floatx4;

#define LOG2E_OVER_8 0.18033688011112042f

// ===== Frag-order layouts (verified r9) =====================================
// Kh chunk(t16,c): ((t16*2+c)*64 + quad*16 + m)*8 halves  (A-frag 16x16x32)
// Qh: same with m=q%16. Vh chunk(t64,dt,ktp): (((t64*8)+dt*2+ktp)*64+quad*16+m)*8
// Wt: ((ctg*16+kc)*64 + quad*16 + m)*8

// ---------------- Kernel 0: W -> frag-order Wt fp16 -------------------------
__global__ __launch_bounds__(256) void wtrans_k(const float* __restrict__ Wq,
                                                const float* __restrict__ Wk,
                                                const float* __restrict__ Wv,
                                                _Float16* __restrict__ Wt) {
    int idx = blockIdx.x * 256 + threadIdx.x;   // 98304 = 3*512*64
    int p = idx >> 15, rem = idx & 32767;
    int k = rem >> 6;      // input row
    int n = rem & 63;      // input col (lane-fast -> coalesced read)
    const float* W = (p == 0) ? Wq : ((p == 1) ? Wk : Wv);
    int ctg = p * 4 + (n >> 4), m = n & 15;
    int kc = k >> 5, quad = (k >> 3) & 3, j = k & 7;
    Wt[(((ctg << 4) + kc) * 64 + (quad << 4) + m) * 8 + j] = (_Float16)W[k * 64 + n];
}

// ---------------- Kernel 1: QKV projection (verified r9) --------------------
#define XS_STRIDE 536
__global__ __launch_bounds__(256) void proj_k(const float* __restrict__ x,
                                              const _Float16* __restrict__ Wt,
                                              const float* __restrict__ bq,
                                              const float* __restrict__ bk,
                                              const float* __restrict__ bv,
                                              _Float16* __restrict__ Qh,
                                              _Float16* __restrict__ Kh,
                                              _Float16* __restrict__ Vh) {
    __shared__ _Float16 xs[16 * XS_STRIDE];

    int tid = threadIdx.x, l = tid & 63, wv = tid >> 6;
    int m = l & 15, quad = l >> 4;
    int row0 = blockIdx.x * 16;

#pragma unroll
    for (int i = 0; i < 8; i++) {
        int idx = tid + i * 256;
        int row = idx >> 7, c4 = idx & 127;
        float4 v = *(const float4*)(x + (row0 + row) * 512 + c4 * 4);
        union { half2v h[2]; uint2 u; } cv;
        cv.h[0][0] = (_Float16)v.x; cv.h[0][1] = (_Float16)v.y;
        cv.h[1][0] = (_Float16)v.z; cv.h[1][1] = (_Float16)v.w;
        *(uint2*)(xs + row * XS_STRIDE + c4 * 4) = cv.u;
    }
    __syncthreads();

    const _Float16* arow = xs + m * XS_STRIDE + quad * 8;

    floatx4 acc[3];
#pragma unroll
    for (int i = 0; i < 3; i++) acc[i] = (floatx4)(0.f);

#pragma unroll 4
    for (int kc = 0; kc < 16; kc++) {
        half8v a = *(const half8v*)(arow + kc * 32);
#pragma unroll
        for (int ct = 0; ct < 3; ct++) {
            int ctg = wv * 3 + ct;
            half8v b = *(const half8v*)(Wt + (((ctg << 4) + kc) * 64 + l) * 8);
            acc[ct] = __builtin_amdgcn_mfma_f32_16x16x32_f16(a, b, acc[ct], 0, 0, 0);
        }
    }

#pragma unroll
    for (int ct = 0; ct < 3; ct++) {
        int ctg = wv * 3 + ct;
        int col = ctg * 16 + m;
        float bias = (ctg < 4) ? bq[col] : ((ctg < 8) ? bk[col - 64] : bv[col - 128]);
        if (ctg < 8) {
            _Float16* dst = (ctg < 4) ? Qh : Kh;
            float scl = (ctg < 4) ? LOG2E_OVER_8 : 1.0f;
            int dd = (ctg & 3) * 16 + m;
            int c = dd >> 5, quadQ = (dd >> 3) & 3, j = dd & 7;
#pragma unroll
            for (int r = 0; r < 4; r++) {
                int row = row0 + quad * 4 + r;
                int chunk = ((row >> 4) << 1) + c;
                dst[(chunk * 64 + quadQ * 16 + (row & 15)) * 8 + j] =
                    (_Float16)((acc[ct][r] + bias) * scl);
            }
        } else {
            int dt = ctg - 8;
            int t64 = row0 >> 6, ktp = (row0 >> 5) & 1, half = (row0 >> 4) & 1;
            int chunk = t64 * 8 + dt * 2 + ktp;
            union { _Float16 h[4]; unsigned long long u; } pk;
#pragma unroll
            for (int r = 0; r < 4; r++) pk.h[r] = (_Float16)(acc[ct][r] + bias);
            *(unsigned long long*)(Vh + (chunk * 64 + quad * 16 + m) * 8 + half * 4) = pk.u;
        }
    }
}

// ---------------- Kernel 2: attention, async LDS staging --------------------
// grid 1024 = qblk(64) x grp(16: os4 x b4, bid&15 -> XCD-pinned K/V slice).
// Block: 2 waves x 32 q = 64 q, all 1024 keys. 16 KB K+V tiles staged via
// global_load_lds (width 16, zero VGPRs), double-buffered; loop order
// [barrier][issue t+1][compute t] so the barrier's vmcnt(0) waits only for
// tile t (landed during t-1's compute) while t+1 flies through compute.
__global__ __launch_bounds__(128) void attn_k(const _Float16* __restrict__ Qh,
                                              const _Float16* __restrict__ Kh,
                                              const _Float16* __restrict__ Vh,
                                              const int* __restrict__ mask,
                                              float* __restrict__ Np,
                                              float* __restrict__ Dp) {
    __shared__ __align__(16) uint4 buf[2][1024];   // 2 x 16 KB

    int tid = threadIdx.x, l = tid & 63, wv = tid >> 6;   // wv 0/1
    int m = l & 15, quad = l >> 4;
    int bid = blockIdx.x;
    int qblk = bid >> 4, grp = bid & 15, os = grp >> 2, b = grp & 3;
    int q0 = qblk * 64 + wv * 32;

    const int* maskb = mask + b * 4096 + os * 1024;
    int az = 0;
#pragma unroll
    for (int i = 0; i < 16; i++) az |= (maskb[l + i * 64] == 0);
    const bool hasz = __any(az);

    // Q B-frags for this wave's 2 q-tiles
    int qt_g = (b * 4096 + q0) >> 4;
    half8v qf[2][2];
#pragma unroll
    for (int qt = 0; qt < 2; qt++)
#pragma unroll
        for (int c = 0; c < 2; c++)
            qf[qt][c] = *(const half8v*)(Qh + (((qt_g + qt) * 2 + c) * 64 + l) * 8);

    int tb0 = (b * 64 + os * 16) * 512;               // uint4 idx of tile 0
    const uint4* gsrc = ((wv == 0) ? (const uint4*)Kh : (const uint4*)Vh) + tb0;
    // wave 0 stages K (slots 0..7), wave 1 stages V (slots 8..15)

    floatx4 oacc[2][4];
#pragma unroll
    for (int qt = 0; qt < 2; qt++)
#pragma unroll
        for (int dt = 0; dt < 4; dt++) oacc[qt][dt] = (floatx4)(0.f);
    float dl[2] = {0.f, 0.f};

    typedef const __attribute__((address_space(1))) void gvoid;
    typedef __attribute__((address_space(3))) void lvoid;

    // issue tile 0
#pragma unroll
    for (int j = 0; j < 8; j++)
        __builtin_amdgcn_global_load_lds(
            (gvoid*)(gsrc + j * 64 + l),
            (lvoid*)(&buf[0][(wv * 8 + j) * 64]), 16, 0, 0);

#pragma unroll 2
    for (int t = 0; t < 16; t++) {
        __syncthreads();   // vmcnt(0) drain == wait for tile t (already landed)
        if (t + 1 < 16) {
            const uint4* gs = gsrc + (t + 1) * 512;
            uint4* bn = &buf[(t + 1) & 1][0];
#pragma unroll
            for (int j = 0; j < 8; j++)
                __builtin_amdgcn_global_load_lds(
                    (gvoid*)(gs + j * 64 + l),
                    (lvoid*)(bn + (wv * 8 + j) * 64), 16, 0, 0);
        }
        const unsigned char* bk = (const unsigned char*)&buf[t & 1][0];
        const unsigned char* bv = bk + 8192;
        uint4 vv[4];
#pragma unroll
        for (int sub = 0; sub < 4; sub++) {
            half8v k0 = *(const half8v*)(bk + (sub * 2 + 0) * 1024 + l * 16);
            half8v k1 = *(const half8v*)(bk + (sub * 2 + 1) * 1024 + l * 16);
            if ((sub & 1) == 0) {
#pragma unroll
                for (int dt = 0; dt < 4; dt++)
                    vv[dt] = *(const uint4*)(bv + (dt * 2 + (sub >> 1)) * 1024 + l * 16);
            }
            half4v pb[2];
#pragma unroll
            for (int qt = 0; qt < 2; qt++) {
                floatx4 sf = (floatx4)(0.f);
                sf = __builtin_amdgcn_mfma_f32_16x16x32_f16(k0, qf[qt][0], sf, 0, 0, 0);
                sf = __builtin_amdgcn_mfma_f32_16x16x32_f16(k1, qf[qt][1], sf, 0, 0, 0);
                float p0 = exp2f(sf[0]), p1 = exp2f(sf[1]);
                float p2 = exp2f(sf[2]), p3 = exp2f(sf[3]);
                dl[qt] += (p0 + p1) + (p2 + p3);
                if (hasz) {   // post-softmax -inf fill (rare path)
                    int kg = t * 64 + sub * 16 + quad * 4;
                    if (maskb[kg + 0] == 0) p0 = -__builtin_inff();
                    if (maskb[kg + 1] == 0) p1 = -__builtin_inff();
                    if (maskb[kg + 2] == 0) p2 = -__builtin_inff();
                    if (maskb[kg + 3] == 0) p3 = -__builtin_inff();
                }
                union { fp16x2 h[2]; half4v h4; } pu;
                pu.h[0] = __builtin_amdgcn_cvt_pkrtz(p0, p1);
                pu.h[1] = __builtin_amdgcn_cvt_pkrtz(p2, p3);
                pb[qt] = pu.h4;
            }
#pragma unroll
            for (int dt = 0; dt < 4; dt++) {
                union { uint4 u; half4v h[2]; } vc; vc.u = vv[dt];
                half4v va = vc.h[sub & 1];
                oacc[0][dt] = __builtin_amdgcn_mfma_f32_16x16x16f16(va, pb[0], oacc[0][dt], 0, 0, 0);
                oacc[1][dt] = __builtin_amdgcn_mfma_f32_16x16x16f16(va, pb[1], oacc[1][dt], 0, 0, 0);
            }
        }
    }

    // epilogue: den + O^T transpose via wave-private LDS (reuse buf)
    __syncthreads();
    float* Tw = (float*)(&buf[0][0]) + wv * (16 * 68);
    int rowb = os * 16384 + b * 4096 + q0;
#pragma unroll
    for (int qt = 0; qt < 2; qt++) {
        float dqt = dl[qt];
        dqt += __shfl_xor(dqt, 16, 64);
        dqt += __shfl_xor(dqt, 32, 64);
        if (l < 16) Dp[rowb + qt * 16 + l] = dqt;
#pragma unroll
        for (int dt = 0; dt < 4; dt++)
#pragma unroll
            for (int r = 0; r < 4; r++)
                Tw[m * 68 + dt * 16 + quad * 4 + r] = oacc[qt][dt][r];
        __builtin_amdgcn_s_waitcnt(0);
#pragma unroll
        for (int g = 0; g < 4; g++) {
            int idx = g * 64 + l;
            int row = idx >> 4, c4 = (idx & 15) * 4;
            float4 v = *(const float4*)(Tw + row * 68 + c4);
            *(float4*)(Np + (rowb + qt * 16 + row) * 64 + c4) = v;
        }
        __builtin_amdgcn_s_waitcnt(0);   // reads done before next qt overwrite
    }
}

// ---------------- Kernel 3: combine 4 key-split partials --------------------
__global__ __launch_bounds__(256) void combine_k(const float* __restrict__ Np,
                                                 const float* __restrict__ Dp,
                                                 float* __restrict__ out) {
    int g = blockIdx.x * 256 + threadIdx.x;   // 1,048,576
    int row = g >> 6;
    float nu = 0.f, d = 0.f;
#pragma unroll
    for (int sp = 0; sp < 4; sp++) {
        nu += Np[sp * 1048576 + g];
        d  += Dp[sp * 16384 + row];
    }
    out[g] = nu / d;
}

extern "C" void kernel_launch(void* const* d_in, const int* in_sizes, int n_in,
                              void* d_out, int out_size, void* d_ws, size_t ws_size,
                              hipStream_t stream) {
    const float* x  = (const float*)d_in[0];
    const int* mask = (const int*)d_in[1];
    const float* Wq = (const float*)d_in[2];
    const float* bq = (const float*)d_in[3];
    const float* Wk = (const float*)d_in[4];
    const float* bk = (const float*)d_in[5];
    const float* Wv = (const float*)d_in[6];
    const float* bv = (const float*)d_in[7];
    float* out = (float*)d_out;

    char* ws = (char*)d_ws;
    _Float16* Wt = (_Float16*)(ws);              // 192 KB frag-order
    _Float16* Qh = (_Float16*)(ws + 0x40000);    // 2 MB frag-order
    _Float16* Kh = (_Float16*)(ws + 0x240000);   // 2 MB frag-order
    _Float16* Vh = (_Float16*)(ws + 0x440000);   // 2 MB V^T frag-order
    float*    Dp = (float*)(ws + 0x640000);      // 256 KB [4][16384]
    float*    Np = (float*)(ws + 0x6C0000);      // 16.78 MB [4][16384][64]

    wtrans_k<<<384, 256, 0, stream>>>(Wq, Wk, Wv, Wt);
    proj_k<<<1024, 256, 0, stream>>>(x, Wt, bq, bk, bv, Qh, Kh, Vh);
    attn_k<<<1024, 128, 0, stream>>>(Qh, Kh, Vh, mask, Np, Dp);
    combine_k<<<4096, 256, 0, stream>>>(Np, Dp, out);
}